// Round 2
// baseline (1260.787 us; speedup 1.0000x reference)
//
#include <hip/hip_runtime.h>
#include <cstdint>

#define K_SEL 4768
#define W75 75
#define CAND_CAP 16384

struct P5 { const float* p[5]; };

__device__ __forceinline__ unsigned fsortkey(float f) {
  unsigned b = __float_as_uint(f);
  return (b & 0x80000000u) ? ~b : (b | 0x80000000u);
}

// ---------------- histogram of sortable-logit top-13 bits per (img,lvl) ----------------
__global__ __launch_bounds__(256) void k_hist(P5 obj, unsigned* ghist) {
  int p = blockIdx.y; int img = p / 5, lvl = p % 5;
  int f = 256 >> lvl; int n = 3 * f * f;
  __shared__ unsigned lh[8192];
  for (int b = threadIdx.x; b < 8192; b += 256) lh[b] = 0;
  __syncthreads();
  int chunk = (n + gridDim.x - 1) / gridDim.x;
  int e0 = blockIdx.x * chunk, e1 = min(n, e0 + chunk);
  const float* src = obj.p[lvl] + (size_t)img * n;
  for (int e = e0 + threadIdx.x; e < e1; e += 256) {
    unsigned sv = fsortkey(src[e]);
    atomicAdd(&lh[sv >> 19], 1u);
  }
  __syncthreads();
  for (int b = threadIdx.x; b < 8192; b += 256) {
    unsigned v = lh[b];
    if (v) atomicAdd(&ghist[(size_t)p * 8192 + b], v);
  }
}

// ---------------- find threshold bin B: count(bin >= B) >= kk --------------------------
__global__ __launch_bounds__(256) void k_thresh(const unsigned* ghist, int* Bthr) {
  int p = blockIdx.x; int lvl = p % 5;
  unsigned kk = (lvl == 4) ? 768u : 1000u;
  const unsigned* h = ghist + (size_t)p * 8192;
  __shared__ unsigned csum[256];
  unsigned s = 0;
  int c = threadIdx.x;
  for (int b = 0; b < 32; ++b) s += h[c * 32 + b];
  csum[c] = s;
  __syncthreads();
  if (threadIdx.x == 0) {
    unsigned acc = 0; int B = 0;
    for (int cc = 255; cc >= 0; --cc) {
      if (acc + csum[cc] >= kk) {
        for (int b = 31; b >= 0; --b) {
          acc += h[cc * 32 + b];
          if (acc >= kk) { B = cc * 32 + b; break; }
        }
        break;
      }
      acc += csum[cc];
    }
    Bthr[p] = B;
  }
}

// ---------------- gather candidates (bin >= B) with unique key64 ------------------------
__global__ __launch_bounds__(256) void k_gather(P5 obj, const int* Bthr, unsigned* cnt,
                                                unsigned long long* ck) {
  int p = blockIdx.y; int img = p / 5, lvl = p % 5;
  int f = 256 >> lvl; int hw = f * f; int n = 3 * hw;
  int e = blockIdx.x * 256 + threadIdx.x;
  if (e >= n) return;
  float v = obj.p[lvl][(size_t)img * n + e];
  unsigned sv = fsortkey(v);
  if ((int)(sv >> 19) >= Bthr[p]) {
    unsigned pos = atomicAdd(&cnt[p], 1u);
    if (pos < CAND_CAP) {
      int a = e / hw;              // hw is power of two -> shift
      int r = e - a * hw;
      unsigned kidx = (unsigned)(r * 3 + a);   // reference flatten order (y*W+x)*A + a
      ck[(size_t)p * CAND_CAP + pos] =
          ((unsigned long long)sv << 32) | (unsigned)(0xFFFFFFFFu - kidx);
    }
  }
}

// ---------------- exact top-kk per level by rank counting (value desc, idx asc) ---------
__global__ __launch_bounds__(256) void k_select(const unsigned* cnt, const unsigned long long* ck,
                                                unsigned* selSV, unsigned* selIdx) {
  int p = blockIdx.y; int img = p / 5, lvl = p % 5;
  int kk = (lvl == 4) ? 768 : 1000;
  int soff = lvl * 1000;
  int Cc = min((int)cnt[p], CAND_CAP);
  int c = blockIdx.x * 256 + threadIdx.x;
  if (c >= Cc) return;
  const unsigned long long* keys = ck + (size_t)p * CAND_CAP;
  unsigned long long kc = keys[c];
  int rank = 0;
#pragma unroll 4
  for (int j = 0; j < Cc; ++j) rank += (keys[j] > kc) ? 1 : 0;
  if (rank < kk) {
    int slot = img * K_SEL + soff + rank;
    selSV[slot]  = (unsigned)(kc >> 32);
    selIdx[slot] = 0xFFFFFFFFu - (unsigned)kc;
  }
}

// ---------------- decode + clip + validity for the 4768 selected per image --------------
__global__ __launch_bounds__(256) void k_decode(P5 del, const float* anchors,
                                                const unsigned* selSV, const unsigned* selIdx,
                                                float* boxP, unsigned long long* keyP) {
  int i = blockIdx.x * 256 + threadIdx.x;
  if (i >= K_SEL) return;
  int img = blockIdx.y;
  int lvl = (i < 4000) ? (i / 1000) : 4;
  int f = 256 >> lvl, hw = f * f;
  const int aoffA[5] = {0, 196608, 245760, 258048, 261120};
  int slot = img * K_SEL + i;
  unsigned k = selIdx[slot];
  unsigned sv = selSV[slot];
  int a = (int)(k % 3u); int r = (int)(k / 3u);
  int y = r >> (8 - lvl); int x = r & (f - 1);
  const float* dp = del.p[lvl] + (size_t)(img * 12 + a * 4) * hw + (size_t)y * f + x;
  float d0 = dp[0], d1 = dp[hw], d2 = dp[2 * hw], d3 = dp[3 * hw];
  const float* ar = anchors + (size_t)(aoffA[lvl] + (int)k) * 4;
  float a0 = ar[0], a1 = ar[1], a2 = ar[2], a3 = ar[3];
  // numpy-faithful, no FMA contraction
  float w = __fsub_rn(a2, a0), h = __fsub_rn(a3, a1);
  float cx = __fadd_rn(a0, __fmul_rn(0.5f, w));
  float cy = __fadd_rn(a1, __fmul_rn(0.5f, h));
  const float CLIP = 4.135166556742356f;     // log(1000/16)
  float dw = fminf(d2, CLIP), dh = fminf(d3, CLIP);
  float pcx = __fadd_rn(__fmul_rn(d0, w), cx);
  float pcy = __fadd_rn(__fmul_rn(d1, h), cy);
  float pw = __fmul_rn(expf(dw), w);
  float ph = __fmul_rn(expf(dh), h);
  float x1 = __fsub_rn(pcx, __fmul_rn(0.5f, pw));
  float y1 = __fsub_rn(pcy, __fmul_rn(0.5f, ph));
  float x2 = __fadd_rn(pcx, __fmul_rn(0.5f, pw));
  float y2 = __fadd_rn(pcy, __fmul_rn(0.5f, ph));
  float x1c = fminf(fmaxf(x1, 0.0f), 1024.0f);
  float y1c = fminf(fmaxf(y1, 0.0f), 1024.0f);
  float x2c = fminf(fmaxf(x2, 0.0f), 1024.0f);
  float y2c = fminf(fmaxf(y2, 0.0f), 1024.0f);
  bool valid = (__fsub_rn(x2c, x1c) >= 1e-3f) && (__fsub_rn(y2c, y1c) >= 1e-3f);
  float* bp = boxP + (size_t)slot * 4;
  bp[0] = x1c; bp[1] = y1c; bp[2] = x2c; bp[3] = y2c;
  unsigned low = 0xFFFFFFFFu - (unsigned)i;   // pos asc tie-break, unique keys
  keyP[slot] = valid ? (((unsigned long long)sv << 32) | low) : (unsigned long long)low;
}

// ---------------- global per-image stable sort by (logit desc, pos asc) via rank --------
__global__ __launch_bounds__(256) void k_sortrank(const unsigned long long* keyP, const float* boxP,
                                                  float* sBox, unsigned* sMeta) {
  __shared__ unsigned long long lk[K_SEL];
  int img = blockIdx.y;
  for (int t = threadIdx.x; t < K_SEL; t += 256) lk[t] = keyP[(size_t)img * K_SEL + t];
  __syncthreads();
  int i = blockIdx.x * 256 + threadIdx.x;
  if (i >= K_SEL) return;
  unsigned long long ki = lk[i];
  int rank = 0;
#pragma unroll 4
  for (int j = 0; j < K_SEL; ++j) rank += (lk[j] > ki) ? 1 : 0;
  int slot = img * K_SEL + i;
  const float* bp = boxP + (size_t)slot * 4;
  float* op = sBox + (size_t)(img * K_SEL + rank) * 4;
  op[0] = bp[0]; op[1] = bp[1]; op[2] = bp[2]; op[3] = bp[3];
  bool valid = (ki >> 32) != 0ULL;
  int pos = (int)(0xFFFFFFFFu - (unsigned)ki);
  int lvl = (pos < 4000) ? pos / 1000 : 4;
  sMeta[img * K_SEL + rank] = valid ? (unsigned)lvl : 255u;
}

// ---------------- IoU computed on OFFSET boxes, bitwise matching the reference ----------
__device__ __forceinline__ bool iou_gt(float rx1, float ry1, float rx2, float ry2, float rar,
                                       float cx1, float cy1, float cx2, float cy2, float car) {
  float ltx = fmaxf(rx1, cx1), lty = fmaxf(ry1, cy1);
  float rbx = fminf(rx2, cx2), rby = fminf(ry2, cy2);
  float wx = fmaxf(__fsub_rn(rbx, ltx), 0.0f);
  float wy = fmaxf(__fsub_rn(rby, lty), 0.0f);
  float inter = __fmul_rn(wx, wy);
  float denom = __fadd_rn(__fsub_rn(__fadd_rn(rar, car), inter), 1e-9f);
  return __fdiv_rn(inter, denom) > 0.7f;
}

// ---------------- path A: 64x64 suppression bitmask ------------------------------------
__global__ __launch_bounds__(64) void k_mask(const float* sBox, const unsigned* sMeta,
                                             unsigned long long* mask) {
  int colb = blockIdx.x, rowb = blockIdx.y, img = blockIdx.z;
  int t = threadIdx.x;
  int i = rowb * 64 + t;
  if (colb < rowb) {                      // all bits have j<i -> zero
    if (i < K_SEL) mask[((size_t)img * K_SEL + i) * W75 + colb] = 0ULL;
    return;
  }
  __shared__ float cx1[64], cy1[64], cx2[64], cy2[64], car[64];
  int j = colb * 64 + t;
  if (j < K_SEL) {
    const float* bp = sBox + (size_t)(img * K_SEL + j) * 4;
    unsigned lv = sMeta[img * K_SEL + j];
    float off = __fmul_rn((float)lv, 1025.0f);
    float ox1 = __fadd_rn(bp[0], off), oy1 = __fadd_rn(bp[1], off);
    float ox2 = __fadd_rn(bp[2], off), oy2 = __fadd_rn(bp[3], off);
    cx1[t] = ox1; cy1[t] = oy1; cx2[t] = ox2; cy2[t] = oy2;
    car[t] = __fmul_rn(__fsub_rn(ox2, ox1), __fsub_rn(oy2, oy1));
  }
  __syncthreads();
  if (i >= K_SEL) return;
  const float* bp = sBox + (size_t)(img * K_SEL + i) * 4;
  unsigned lvi = sMeta[img * K_SEL + i];
  float off = __fmul_rn((float)lvi, 1025.0f);
  float rx1 = __fadd_rn(bp[0], off), ry1 = __fadd_rn(bp[1], off);
  float rx2 = __fadd_rn(bp[2], off), ry2 = __fadd_rn(bp[3], off);
  float rar = __fmul_rn(__fsub_rn(rx2, rx1), __fsub_rn(ry2, ry1));
  unsigned long long bits = 0;
  int jmax = min(64, K_SEL - colb * 64);
  for (int jj = 0; jj < jmax; ++jj) {
    int j2 = colb * 64 + jj;
    if (j2 <= i) continue;
    if (iou_gt(rx1, ry1, rx2, ry2, rar, cx1[jj], cy1[jj], cx2[jj], cy2[jj], car[jj]))
      bits |= (1ULL << jj);
  }
  mask[((size_t)img * K_SEL + i) * W75 + colb] = bits;
}

// ---------------- path A: sequential bit-scan + compaction into d_out -------------------
__global__ __launch_bounds__(64) void k_scan(const float* sBox, const unsigned* sMeta,
                                             const unsigned long long* mask, float* out) {
  int img = blockIdx.x;
  int t = threadIdx.x;
  __shared__ unsigned long long remv[W75];
  for (int w = t; w < W75; w += 64) remv[w] = 0ULL;
  __syncthreads();
  int outc = 0;
  for (int i = 0; i < K_SEL; ++i) {
    __syncthreads();
    unsigned mv = sMeta[img * K_SEL + i];
    if (mv == 255u) continue;                       // invalid, never kept
    bool sup = (remv[i >> 6] >> (i & 63)) & 1ULL;   // uniform broadcast read
    if (!sup) {
      if (t < 4) out[((size_t)img * 1000 + outc) * 4 + t] = sBox[((size_t)img * K_SEL + i) * 4 + t];
      ++outc;
      if (outc == 1000) break;                      // later keeps can't reach output
      const unsigned long long* mrow = mask + ((size_t)img * K_SEL + i) * W75;
      for (int w = t; w < W75; w += 64) remv[w] |= mrow[w];
    }
  }
}

// ---------------- path B fallback (small ws): barrier-sequential NMS --------------------
__global__ __launch_bounds__(256) void k_nmsseq(const float* sBox, const unsigned* sMeta,
                                                float* out) {
  int img = blockIdx.x;
  int t = threadIdx.x;
  __shared__ unsigned char keep[K_SEL];
  for (int i = t; i < K_SEL; i += 256) keep[i] = (sMeta[img * K_SEL + i] != 255u) ? 1 : 0;
  __syncthreads();
  for (int i = 0; i < K_SEL; ++i) {
    __syncthreads();
    if (!keep[i]) continue;
    unsigned lvi = sMeta[img * K_SEL + i];
    const float* bp = sBox + (size_t)(img * K_SEL + i) * 4;
    float off = __fmul_rn((float)lvi, 1025.0f);
    float rx1 = __fadd_rn(bp[0], off), ry1 = __fadd_rn(bp[1], off);
    float rx2 = __fadd_rn(bp[2], off), ry2 = __fadd_rn(bp[3], off);
    float rar = __fmul_rn(__fsub_rn(rx2, rx1), __fsub_rn(ry2, ry1));
    for (int j = i + 1 + t; j < K_SEL; j += 256) {
      if (!keep[j]) continue;
      unsigned lvj = sMeta[img * K_SEL + j];
      if (lvj != lvi) continue;
      const float* bq = sBox + (size_t)(img * K_SEL + j) * 4;
      float qx1 = __fadd_rn(bq[0], off), qy1 = __fadd_rn(bq[1], off);
      float qx2 = __fadd_rn(bq[2], off), qy2 = __fadd_rn(bq[3], off);
      float qar = __fmul_rn(__fsub_rn(qx2, qx1), __fsub_rn(qy2, qy1));
      if (iou_gt(rx1, ry1, rx2, ry2, rar, qx1, qy1, qx2, qy2, qar)) keep[j] = 0;
    }
  }
  __syncthreads();
  if (t == 0) {
    int outc = 0;
    for (int i = 0; i < K_SEL && outc < 1000; ++i) {
      if (!keep[i]) continue;
      const float* bp = sBox + (size_t)(img * K_SEL + i) * 4;
      float* op = out + ((size_t)img * 1000 + outc) * 4;
      op[0] = bp[0]; op[1] = bp[1]; op[2] = bp[2]; op[3] = bp[3];
      ++outc;
    }
  }
}

extern "C" void kernel_launch(void* const* d_in, const int* in_sizes, int n_in,
                              void* d_out, int out_size, void* d_ws, size_t ws_size,
                              hipStream_t stream) {
  (void)in_sizes; (void)n_in;
  // setup_inputs() dict order is INTERLEAVED: obj_l0, delta_l0, obj_l1, delta_l1, ..., anchors
  P5 obj, del;
  for (int i = 0; i < 5; ++i) {
    obj.p[i] = (const float*)d_in[2 * i];
    del.p[i] = (const float*)d_in[2 * i + 1];
  }
  const float* anchors = (const float*)d_in[10];
  float* out = (float*)d_out;
  char* ws = (char*)d_ws;

  // ws layout (bytes)
  unsigned* ghist             = (unsigned*)(ws + 0);             // 40*8192*4 = 1310720
  unsigned* cnt               = (unsigned*)(ws + 1310720);       // 160
  int* Bthr                   = (int*)(ws + 1310880);            // 160
  unsigned long long* candK   = (unsigned long long*)(ws + 1311040);   // 40*16384*8 = 5242880
  unsigned* selSV             = (unsigned*)(ws + 6553920);       // 152576
  unsigned* selIdx            = (unsigned*)(ws + 6706496);       // 152576
  float* boxP                 = (float*)(ws + 6859072);          // 610304
  unsigned long long* keyP    = (unsigned long long*)(ws + 7469376);   // 305152
  float* sBox                 = (float*)(ws + 7774528);          // 610304
  unsigned* sMeta             = (unsigned*)(ws + 8384832);       // 152576
  unsigned long long* mask    = (unsigned long long*)(ws + 8537408);   // 8*4768*75*8 = 22878720
  const size_t NEED_A = 31416128ULL;   // everything incl. mask
  const size_t NEED_B = 8537408ULL;    // everything except mask
  bool pathA = ws_size >= NEED_A;
  bool pathB = !pathA && ws_size >= NEED_B;

  hipMemsetAsync(d_out, 0, (size_t)out_size * 4, stream);        // zero-padded output
  if (!pathA && !pathB) return;                                  // ws too small: diagnose, don't fault

  hipMemsetAsync(ws, 0, 1311040, stream);                        // hist + counters + Bthr

  k_hist   <<<dim3(16, 40), 256, 0, stream>>>(obj, ghist);
  k_thresh <<<40, 256, 0, stream>>>(ghist, Bthr);
  k_gather <<<dim3(768, 40), 256, 0, stream>>>(obj, Bthr, cnt, candK);
  k_select <<<dim3(64, 40), 256, 0, stream>>>(cnt, candK, selSV, selIdx);
  k_decode <<<dim3(19, 8), 256, 0, stream>>>(del, anchors, selSV, selIdx, boxP, keyP);
  k_sortrank<<<dim3(19, 8), 256, 0, stream>>>(keyP, boxP, sBox, sMeta);
  if (pathA) {
    k_mask <<<dim3(W75, W75, 8), 64, 0, stream>>>(sBox, sMeta, mask);
    k_scan <<<8, 64, 0, stream>>>(sBox, sMeta, mask, out);
  } else {
    k_nmsseq<<<8, 256, 0, stream>>>(sBox, sMeta, out);
  }
}

// Round 3
// 745.607 us; speedup vs baseline: 1.6910x; 1.6910x over previous
//
#include <hip/hip_runtime.h>
#include <cstdint>

#define K_SEL 4768
#define W75 75
#define CAND_CAP 16384

struct P5 { const float* p[5]; };

__device__ __forceinline__ unsigned fsortkey(float f) {
  unsigned b = __float_as_uint(f);
  return (b & 0x80000000u) ? ~b : (b | 0x80000000u);
}

// ---------------- histogram of sortable-logit top-13 bits per (img,lvl) ----------------
__global__ __launch_bounds__(256) void k_hist(P5 obj, unsigned* ghist) {
  int p = blockIdx.y; int img = p / 5, lvl = p % 5;
  int f = 256 >> lvl; int n = 3 * f * f;
  __shared__ unsigned lh[8192];
  for (int b = threadIdx.x; b < 8192; b += 256) lh[b] = 0;
  __syncthreads();
  int chunk = (n + gridDim.x - 1) / gridDim.x;
  int e0 = blockIdx.x * chunk, e1 = min(n, e0 + chunk);
  const float* src = obj.p[lvl] + (size_t)img * n;
  for (int e = e0 + threadIdx.x; e < e1; e += 256) {
    unsigned sv = fsortkey(src[e]);
    atomicAdd(&lh[sv >> 19], 1u);
  }
  __syncthreads();
  for (int b = threadIdx.x; b < 8192; b += 256) {
    unsigned v = lh[b];
    if (v) atomicAdd(&ghist[(size_t)p * 8192 + b], v);
  }
}

// ---------------- find threshold bin B: count(bin >= B) >= kk --------------------------
__global__ __launch_bounds__(256) void k_thresh(const unsigned* ghist, int* Bthr) {
  int p = blockIdx.x; int lvl = p % 5;
  unsigned kk = (lvl == 4) ? 768u : 1000u;
  const unsigned* h = ghist + (size_t)p * 8192;
  __shared__ unsigned csum[256];
  unsigned s = 0;
  int c = threadIdx.x;
  for (int b = 0; b < 32; ++b) s += h[c * 32 + b];
  csum[c] = s;
  __syncthreads();
  if (threadIdx.x == 0) {
    unsigned acc = 0; int B = 0;
    for (int cc = 255; cc >= 0; --cc) {
      if (acc + csum[cc] >= kk) {
        for (int b = 31; b >= 0; --b) {
          acc += h[cc * 32 + b];
          if (acc >= kk) { B = cc * 32 + b; break; }
        }
        break;
      }
      acc += csum[cc];
    }
    Bthr[p] = B;
  }
}

// ------- gather candidates (bin >= B), wave-aggregated atomics, grid-stride ------------
__global__ __launch_bounds__(256) void k_gather(P5 obj, const int* Bthr, unsigned* cnt,
                                                unsigned long long* ck) {
  int p = blockIdx.y; int img = p / 5, lvl = p % 5;
  int f = 256 >> lvl; int hw = f * f; int n = 3 * hw;
  int B = Bthr[p];
  int shift = 2 * (8 - lvl);
  const float* src = obj.p[lvl] + (size_t)img * n;
  unsigned long long* dst = ck + (size_t)p * CAND_CAP;
  int lane = threadIdx.x & 63;
  for (int e = blockIdx.x * 256 + threadIdx.x; e < n; e += gridDim.x * 256) {
    float v = src[e];
    unsigned sv = fsortkey(v);
    bool pass = (int)(sv >> 19) >= B;
    unsigned long long m = __ballot(pass);
    if (m) {
      int leader = __ffsll(m) - 1;
      unsigned base = 0;
      if (lane == leader) base = atomicAdd(&cnt[p], (unsigned)__popcll(m));
      base = __shfl(base, leader);
      if (pass) {
        unsigned pos = base + (unsigned)__popcll(m & ((1ULL << lane) - 1ULL));
        if (pos < CAND_CAP) {
          int a = e >> shift;            // e / hw
          int r = e & (hw - 1);          // e % hw
          unsigned kidx = (unsigned)(r * 3 + a);   // reference flatten order (y*W+x)*A + a
          dst[pos] = ((unsigned long long)sv << 32) | (unsigned)(0xFFFFFFFFu - kidx);
        }
      }
    }
  }
}

// ---------------- exact top-kk per level by rank counting (value desc, idx asc) ---------
__global__ __launch_bounds__(256) void k_select(const unsigned* cnt, const unsigned long long* ck,
                                                unsigned* selSV, unsigned* selIdx) {
  int p = blockIdx.y; int img = p / 5, lvl = p % 5;
  int kk = (lvl == 4) ? 768 : 1000;
  int soff = lvl * 1000;
  int Cc = min((int)cnt[p], CAND_CAP);
  int c = blockIdx.x * 256 + threadIdx.x;
  if (c >= Cc) return;
  const unsigned long long* keys = ck + (size_t)p * CAND_CAP;
  unsigned long long kc = keys[c];
  int rank = 0;
#pragma unroll 4
  for (int j = 0; j < Cc; ++j) rank += (keys[j] > kc) ? 1 : 0;
  if (rank < kk) {
    int slot = img * K_SEL + soff + rank;
    selSV[slot]  = (unsigned)(kc >> 32);
    selIdx[slot] = 0xFFFFFFFFu - (unsigned)kc;
  }
}

// ---------------- decode + clip + validity for the 4768 selected per image --------------
__global__ __launch_bounds__(256) void k_decode(P5 del, const float* anchors,
                                                const unsigned* selSV, const unsigned* selIdx,
                                                float* boxP, unsigned long long* keyP) {
  int i = blockIdx.x * 256 + threadIdx.x;
  if (i >= K_SEL) return;
  int img = blockIdx.y;
  int lvl = (i < 4000) ? (i / 1000) : 4;
  int f = 256 >> lvl, hw = f * f;
  const int aoffA[5] = {0, 196608, 245760, 258048, 261120};
  int slot = img * K_SEL + i;
  unsigned k = selIdx[slot];
  unsigned sv = selSV[slot];
  int a = (int)(k % 3u); int r = (int)(k / 3u);
  int y = r >> (8 - lvl); int x = r & (f - 1);
  const float* dp = del.p[lvl] + (size_t)(img * 12 + a * 4) * hw + (size_t)y * f + x;
  float d0 = dp[0], d1 = dp[hw], d2 = dp[2 * hw], d3 = dp[3 * hw];
  const float* ar = anchors + (size_t)(aoffA[lvl] + (int)k) * 4;
  float a0 = ar[0], a1 = ar[1], a2 = ar[2], a3 = ar[3];
  // numpy-faithful, no FMA contraction
  float w = __fsub_rn(a2, a0), h = __fsub_rn(a3, a1);
  float cx = __fadd_rn(a0, __fmul_rn(0.5f, w));
  float cy = __fadd_rn(a1, __fmul_rn(0.5f, h));
  const float CLIP = 4.135166556742356f;     // log(1000/16)
  float dw = fminf(d2, CLIP), dh = fminf(d3, CLIP);
  float pcx = __fadd_rn(__fmul_rn(d0, w), cx);
  float pcy = __fadd_rn(__fmul_rn(d1, h), cy);
  float pw = __fmul_rn(expf(dw), w);
  float ph = __fmul_rn(expf(dh), h);
  float x1 = __fsub_rn(pcx, __fmul_rn(0.5f, pw));
  float y1 = __fsub_rn(pcy, __fmul_rn(0.5f, ph));
  float x2 = __fadd_rn(pcx, __fmul_rn(0.5f, pw));
  float y2 = __fadd_rn(pcy, __fmul_rn(0.5f, ph));
  float x1c = fminf(fmaxf(x1, 0.0f), 1024.0f);
  float y1c = fminf(fmaxf(y1, 0.0f), 1024.0f);
  float x2c = fminf(fmaxf(x2, 0.0f), 1024.0f);
  float y2c = fminf(fmaxf(y2, 0.0f), 1024.0f);
  bool valid = (__fsub_rn(x2c, x1c) >= 1e-3f) && (__fsub_rn(y2c, y1c) >= 1e-3f);
  float* bp = boxP + (size_t)slot * 4;
  bp[0] = x1c; bp[1] = y1c; bp[2] = x2c; bp[3] = y2c;
  unsigned low = 0xFFFFFFFFu - (unsigned)i;   // pos asc tie-break, unique keys
  keyP[slot] = valid ? (((unsigned long long)sv << 32) | low) : (unsigned long long)low;
}

// ---------------- global per-image stable sort by (logit desc, pos asc) via rank --------
__global__ __launch_bounds__(256) void k_sortrank(const unsigned long long* keyP, const float* boxP,
                                                  float* sBox, unsigned* sMeta) {
  __shared__ unsigned long long lk[K_SEL];
  int img = blockIdx.y;
  for (int t = threadIdx.x; t < K_SEL; t += 256) lk[t] = keyP[(size_t)img * K_SEL + t];
  __syncthreads();
  int i = blockIdx.x * 256 + threadIdx.x;
  if (i >= K_SEL) return;
  unsigned long long ki = lk[i];
  int rank = 0;
#pragma unroll 4
  for (int j = 0; j < K_SEL; ++j) rank += (lk[j] > ki) ? 1 : 0;
  int slot = img * K_SEL + i;
  const float* bp = boxP + (size_t)slot * 4;
  float* op = sBox + (size_t)(img * K_SEL + rank) * 4;
  op[0] = bp[0]; op[1] = bp[1]; op[2] = bp[2]; op[3] = bp[3];
  bool valid = (ki >> 32) != 0ULL;
  int pos = (int)(0xFFFFFFFFu - (unsigned)ki);
  int lvl = (pos < 4000) ? pos / 1000 : 4;
  sMeta[img * K_SEL + rank] = valid ? (unsigned)lvl : 255u;
}

// ---------------- IoU computed on OFFSET boxes, bitwise matching the reference ----------
__device__ __forceinline__ bool iou_gt(float rx1, float ry1, float rx2, float ry2, float rar,
                                       float cx1, float cy1, float cx2, float cy2, float car) {
  float ltx = fmaxf(rx1, cx1), lty = fmaxf(ry1, cy1);
  float rbx = fminf(rx2, cx2), rby = fminf(ry2, cy2);
  float wx = fmaxf(__fsub_rn(rbx, ltx), 0.0f);
  float wy = fmaxf(__fsub_rn(rby, lty), 0.0f);
  float inter = __fmul_rn(wx, wy);
  float denom = __fadd_rn(__fsub_rn(__fadd_rn(rar, car), inter), 1e-9f);
  return __fdiv_rn(inter, denom) > 0.7f;
}

// ---------------- 64x64 suppression bitmask --------------------------------------------
__global__ __launch_bounds__(64) void k_mask(const float* sBox, const unsigned* sMeta,
                                             unsigned long long* mask) {
  int colb = blockIdx.x, rowb = blockIdx.y, img = blockIdx.z;
  int t = threadIdx.x;
  int i = rowb * 64 + t;
  if (colb < rowb) {                      // all bits have j<i -> zero
    if (i < K_SEL) mask[((size_t)img * K_SEL + i) * W75 + colb] = 0ULL;
    return;
  }
  __shared__ float cx1[64], cy1[64], cx2[64], cy2[64], car[64];
  int j = colb * 64 + t;
  if (j < K_SEL) {
    const float* bp = sBox + (size_t)(img * K_SEL + j) * 4;
    unsigned lv = sMeta[img * K_SEL + j];
    float off = __fmul_rn((float)lv, 1025.0f);
    float ox1 = __fadd_rn(bp[0], off), oy1 = __fadd_rn(bp[1], off);
    float ox2 = __fadd_rn(bp[2], off), oy2 = __fadd_rn(bp[3], off);
    cx1[t] = ox1; cy1[t] = oy1; cx2[t] = ox2; cy2[t] = oy2;
    car[t] = __fmul_rn(__fsub_rn(ox2, ox1), __fsub_rn(oy2, oy1));
  }
  __syncthreads();
  if (i >= K_SEL) return;
  const float* bp = sBox + (size_t)(img * K_SEL + i) * 4;
  unsigned lvi = sMeta[img * K_SEL + i];
  float off = __fmul_rn((float)lvi, 1025.0f);
  float rx1 = __fadd_rn(bp[0], off), ry1 = __fadd_rn(bp[1], off);
  float rx2 = __fadd_rn(bp[2], off), ry2 = __fadd_rn(bp[3], off);
  float rar = __fmul_rn(__fsub_rn(rx2, rx1), __fsub_rn(ry2, ry1));
  unsigned long long bits = 0;
  int jmax = min(64, K_SEL - colb * 64);
  for (int jj = 0; jj < jmax; ++jj) {
    int j2 = colb * 64 + jj;
    if (j2 <= i) continue;
    if (iou_gt(rx1, ry1, rx2, ry2, rar, cx1[jj], cy1[jj], cx2[jj], cy2[jj], car[jj]))
      bits |= (1ULL << jj);
  }
  mask[((size_t)img * K_SEL + i) * W75 + colb] = bits;
}

// --------- single-wave, barrier-free bit-scan + compaction into d_out -------------------
// remv is distributed across the wave: lane t holds words t (r0) and 64+t (r1, t<11).
__global__ __launch_bounds__(64) void k_scan(const float* sBox, const unsigned* sMeta,
                                             const unsigned long long* mask, float* out) {
  int img = blockIdx.x;
  int t = threadIdx.x;
  unsigned long long r0 = 0ULL, r1 = 0ULL;
  const unsigned long long* mbase = mask + (size_t)img * K_SEL * W75;
  const float4* boxes4 = (const float4*)(sBox + (size_t)img * K_SEL * 4);
  float4* out4 = (float4*)(out + (size_t)img * 1000 * 4);
  const unsigned* meta = sMeta + (size_t)img * K_SEL;
  int outc = 0;
  for (int c = 0; c < W75; ++c) {
    int i = c * 64 + t;
    bool valid = (i < K_SEL) && (meta[min(i, K_SEL - 1)] != 255u) && (i < K_SEL);
    unsigned long long validm = __ballot(valid);
    unsigned long long cur = (c < 64) ? __shfl(r0, c) : __shfl(r1, c - 64);
    unsigned long long wself = (i < K_SEL) ? mbase[(size_t)i * W75 + c] : 0ULL;
    unsigned long long candm = validm & ~cur;
    unsigned long long keepm = 0ULL;
    int base = outc;
    while (candm) {
      int b = __ffsll(candm) - 1;
      keepm |= (1ULL << b);
      ++outc;
      if (outc == 1000) break;
      unsigned long long wb = __shfl(wself, b);
      candm &= candm - 1;        // clear bit b
      candm &= ~wb;              // suppress within-chunk
    }
    if (keepm) {
      bool kept = (keepm >> t) & 1ULL;
      if (kept) {
        int rank = (int)__popcll(keepm & ((1ULL << t) - 1ULL));
        out4[base + rank] = boxes4[i];
      }
    }
    if (outc >= 1000) break;
    // OR kept rows into distributed remv, 4 at a time (independent loads overlap)
    unsigned long long km = keepm;
    while (km) {
      int b0 = __ffsll(km) - 1; km &= km - 1;
      int b1 = -1, b2 = -1, b3 = -1;
      if (km) { b1 = __ffsll(km) - 1; km &= km - 1; }
      if (km) { b2 = __ffsll(km) - 1; km &= km - 1; }
      if (km) { b3 = __ffsll(km) - 1; km &= km - 1; }
      const unsigned long long* row0 = mbase + (size_t)(c * 64 + b0) * W75;
      const unsigned long long* row1 = (b1 >= 0) ? mbase + (size_t)(c * 64 + b1) * W75 : row0;
      const unsigned long long* row2 = (b2 >= 0) ? mbase + (size_t)(c * 64 + b2) * W75 : row0;
      const unsigned long long* row3 = (b3 >= 0) ? mbase + (size_t)(c * 64 + b3) * W75 : row0;
      unsigned long long v0 = row0[t];
      unsigned long long v1 = (b1 >= 0) ? row1[t] : 0ULL;
      unsigned long long v2 = (b2 >= 0) ? row2[t] : 0ULL;
      unsigned long long v3 = (b3 >= 0) ? row3[t] : 0ULL;
      r0 |= v0 | v1 | v2 | v3;
      if (t < W75 - 64) {
        unsigned long long u0 = row0[64 + t];
        unsigned long long u1 = (b1 >= 0) ? row1[64 + t] : 0ULL;
        unsigned long long u2 = (b2 >= 0) ? row2[64 + t] : 0ULL;
        unsigned long long u3 = (b3 >= 0) ? row3[64 + t] : 0ULL;
        r1 |= u0 | u1 | u2 | u3;
      }
    }
  }
}

// ---------------- path B fallback (small ws): barrier-sequential NMS --------------------
__global__ __launch_bounds__(256) void k_nmsseq(const float* sBox, const unsigned* sMeta,
                                                float* out) {
  int img = blockIdx.x;
  int t = threadIdx.x;
  __shared__ unsigned char keep[K_SEL];
  for (int i = t; i < K_SEL; i += 256) keep[i] = (sMeta[img * K_SEL + i] != 255u) ? 1 : 0;
  __syncthreads();
  for (int i = 0; i < K_SEL; ++i) {
    __syncthreads();
    if (!keep[i]) continue;
    unsigned lvi = sMeta[img * K_SEL + i];
    const float* bp = sBox + (size_t)(img * K_SEL + i) * 4;
    float off = __fmul_rn((float)lvi, 1025.0f);
    float rx1 = __fadd_rn(bp[0], off), ry1 = __fadd_rn(bp[1], off);
    float rx2 = __fadd_rn(bp[2], off), ry2 = __fadd_rn(bp[3], off);
    float rar = __fmul_rn(__fsub_rn(rx2, rx1), __fsub_rn(ry2, ry1));
    for (int j = i + 1 + t; j < K_SEL; j += 256) {
      if (!keep[j]) continue;
      unsigned lvj = sMeta[img * K_SEL + j];
      if (lvj != lvi) continue;
      const float* bq = sBox + (size_t)(img * K_SEL + j) * 4;
      float qx1 = __fadd_rn(bq[0], off), qy1 = __fadd_rn(bq[1], off);
      float qx2 = __fadd_rn(bq[2], off), qy2 = __fadd_rn(bq[3], off);
      float qar = __fmul_rn(__fsub_rn(qx2, qx1), __fsub_rn(qy2, qy1));
      if (iou_gt(rx1, ry1, rx2, ry2, rar, qx1, qy1, qx2, qy2, qar)) keep[j] = 0;
    }
  }
  __syncthreads();
  if (t == 0) {
    int outc = 0;
    for (int i = 0; i < K_SEL && outc < 1000; ++i) {
      if (!keep[i]) continue;
      const float* bp = sBox + (size_t)(img * K_SEL + i) * 4;
      float* op = out + ((size_t)img * 1000 + outc) * 4;
      op[0] = bp[0]; op[1] = bp[1]; op[2] = bp[2]; op[3] = bp[3];
      ++outc;
    }
  }
}

extern "C" void kernel_launch(void* const* d_in, const int* in_sizes, int n_in,
                              void* d_out, int out_size, void* d_ws, size_t ws_size,
                              hipStream_t stream) {
  (void)in_sizes; (void)n_in;
  // setup_inputs() dict order is INTERLEAVED: obj_l0, delta_l0, obj_l1, delta_l1, ..., anchors
  P5 obj, del;
  for (int i = 0; i < 5; ++i) {
    obj.p[i] = (const float*)d_in[2 * i];
    del.p[i] = (const float*)d_in[2 * i + 1];
  }
  const float* anchors = (const float*)d_in[10];
  float* out = (float*)d_out;
  char* ws = (char*)d_ws;

  // ws layout (bytes)
  unsigned* ghist             = (unsigned*)(ws + 0);             // 40*8192*4 = 1310720
  unsigned* cnt               = (unsigned*)(ws + 1310720);       // 160
  int* Bthr                   = (int*)(ws + 1310880);            // 160
  unsigned long long* candK   = (unsigned long long*)(ws + 1311040);   // 40*16384*8 = 5242880
  unsigned* selSV             = (unsigned*)(ws + 6553920);       // 152576
  unsigned* selIdx            = (unsigned*)(ws + 6706496);       // 152576
  float* boxP                 = (float*)(ws + 6859072);          // 610304
  unsigned long long* keyP    = (unsigned long long*)(ws + 7469376);   // 305152
  float* sBox                 = (float*)(ws + 7774528);          // 610304
  unsigned* sMeta             = (unsigned*)(ws + 8384832);       // 152576
  unsigned long long* mask    = (unsigned long long*)(ws + 8537408);   // 8*4768*75*8 = 22878720
  const size_t NEED_A = 31416128ULL;   // everything incl. mask
  const size_t NEED_B = 8537408ULL;    // everything except mask
  bool pathA = ws_size >= NEED_A;
  bool pathB = !pathA && ws_size >= NEED_B;

  hipMemsetAsync(d_out, 0, (size_t)out_size * 4, stream);        // zero-padded output
  if (!pathA && !pathB) return;                                  // ws too small: diagnose, don't fault

  hipMemsetAsync(ws, 0, 1311040, stream);                        // hist + counters + Bthr

  k_hist   <<<dim3(8, 40), 256, 0, stream>>>(obj, ghist);
  k_thresh <<<40, 256, 0, stream>>>(ghist, Bthr);
  k_gather <<<dim3(64, 40), 256, 0, stream>>>(obj, Bthr, cnt, candK);
  k_select <<<dim3(64, 40), 256, 0, stream>>>(cnt, candK, selSV, selIdx);
  k_decode <<<dim3(19, 8), 256, 0, stream>>>(del, anchors, selSV, selIdx, boxP, keyP);
  k_sortrank<<<dim3(19, 8), 256, 0, stream>>>(keyP, boxP, sBox, sMeta);
  if (pathA) {
    k_mask <<<dim3(W75, W75, 8), 64, 0, stream>>>(sBox, sMeta, mask);
    k_scan <<<8, 64, 0, stream>>>(sBox, sMeta, mask, out);
  } else {
    k_nmsseq<<<8, 256, 0, stream>>>(sBox, sMeta, out);
  }
}

// Round 4
// 657.561 us; speedup vs baseline: 1.9174x; 1.1339x over previous
//
#include <hip/hip_runtime.h>
#include <cstdint>

#define K_SEL 4768
#define W75 75
#define CAND_CAP 16384

struct P5 { const float* p[5]; };

__device__ __forceinline__ unsigned fsortkey(float f) {
  unsigned b = __float_as_uint(f);
  return (b & 0x80000000u) ? ~b : (b | 0x80000000u);
}

// ---------------- histogram of sortable-logit top-13 bits per (img,lvl) ----------------
__global__ __launch_bounds__(256) void k_hist(P5 obj, unsigned* ghist) {
  int p = blockIdx.y; int img = p / 5, lvl = p % 5;
  int f = 256 >> lvl; int n = 3 * f * f;
  __shared__ unsigned lh[8192];
  for (int b = threadIdx.x; b < 8192; b += 256) lh[b] = 0;
  __syncthreads();
  int chunk = (n + gridDim.x - 1) / gridDim.x;
  int e0 = blockIdx.x * chunk, e1 = min(n, e0 + chunk);
  const float* src = obj.p[lvl] + (size_t)img * n;
  for (int e = e0 + threadIdx.x; e < e1; e += 256) {
    unsigned sv = fsortkey(src[e]);
    atomicAdd(&lh[sv >> 19], 1u);
  }
  __syncthreads();
  for (int b = threadIdx.x; b < 8192; b += 256) {
    unsigned v = lh[b];
    if (v) atomicAdd(&ghist[(size_t)p * 8192 + b], v);
  }
}

// ---------------- find threshold bin B: count(bin >= B) >= kk --------------------------
__global__ __launch_bounds__(256) void k_thresh(const unsigned* ghist, int* Bthr) {
  int p = blockIdx.x; int lvl = p % 5;
  unsigned kk = (lvl == 4) ? 768u : 1000u;
  const unsigned* h = ghist + (size_t)p * 8192;
  __shared__ unsigned csum[256];
  unsigned s = 0;
  int c = threadIdx.x;
  for (int b = 0; b < 32; ++b) s += h[c * 32 + b];
  csum[c] = s;
  __syncthreads();
  if (threadIdx.x == 0) {
    unsigned acc = 0; int B = 0;
    for (int cc = 255; cc >= 0; --cc) {
      if (acc + csum[cc] >= kk) {
        for (int b = 31; b >= 0; --b) {
          acc += h[cc * 32 + b];
          if (acc >= kk) { B = cc * 32 + b; break; }
        }
        break;
      }
      acc += csum[cc];
    }
    Bthr[p] = B;
  }
}

// ------- gather candidates (bin >= B), wave-aggregated atomics, grid-stride ------------
__global__ __launch_bounds__(256) void k_gather(P5 obj, const int* Bthr, unsigned* cnt,
                                                unsigned long long* ck) {
  int p = blockIdx.y; int img = p / 5, lvl = p % 5;
  int f = 256 >> lvl; int hw = f * f; int n = 3 * hw;
  int B = Bthr[p];
  int shift = 2 * (8 - lvl);
  const float* src = obj.p[lvl] + (size_t)img * n;
  unsigned long long* dst = ck + (size_t)p * CAND_CAP;
  int lane = threadIdx.x & 63;
  for (int e = blockIdx.x * 256 + threadIdx.x; e < n; e += gridDim.x * 256) {
    float v = src[e];
    unsigned sv = fsortkey(v);
    bool pass = (int)(sv >> 19) >= B;
    unsigned long long m = __ballot(pass);
    if (m) {
      int leader = __ffsll(m) - 1;
      unsigned base = 0;
      if (lane == leader) base = atomicAdd(&cnt[p], (unsigned)__popcll(m));
      base = __shfl(base, leader);
      if (pass) {
        unsigned pos = base + (unsigned)__popcll(m & ((1ULL << lane) - 1ULL));
        if (pos < CAND_CAP) {
          int a = e >> shift;            // e / hw
          int r = e & (hw - 1);          // e % hw
          unsigned kidx = (unsigned)(r * 3 + a);   // reference flatten order (y*W+x)*A + a
          dst[pos] = ((unsigned long long)sv << 32) | (unsigned)(0xFFFFFFFFu - kidx);
        }
      }
    }
  }
}

// ---------------- exact top-kk per level by rank counting (value desc, idx asc) ---------
__global__ __launch_bounds__(256) void k_select(const unsigned* cnt, const unsigned long long* ck,
                                                unsigned* selSV, unsigned* selIdx) {
  int p = blockIdx.y; int img = p / 5, lvl = p % 5;
  int kk = (lvl == 4) ? 768 : 1000;
  int soff = lvl * 1000;
  int Cc = min((int)cnt[p], CAND_CAP);
  int c = blockIdx.x * 256 + threadIdx.x;
  if (c >= Cc) return;
  const unsigned long long* keys = ck + (size_t)p * CAND_CAP;
  unsigned long long kc = keys[c];
  int rank = 0;
#pragma unroll 4
  for (int j = 0; j < Cc; ++j) rank += (keys[j] > kc) ? 1 : 0;
  if (rank < kk) {
    int slot = img * K_SEL + soff + rank;
    selSV[slot]  = (unsigned)(kc >> 32);
    selIdx[slot] = 0xFFFFFFFFu - (unsigned)kc;
  }
}

// ---------------- decode + clip + validity for the 4768 selected per image --------------
__global__ __launch_bounds__(256) void k_decode(P5 del, const float* anchors,
                                                const unsigned* selSV, const unsigned* selIdx,
                                                float* boxP, unsigned long long* keyP) {
  int i = blockIdx.x * 256 + threadIdx.x;
  if (i >= K_SEL) return;
  int img = blockIdx.y;
  int lvl = (i < 4000) ? (i / 1000) : 4;
  int f = 256 >> lvl, hw = f * f;
  const int aoffA[5] = {0, 196608, 245760, 258048, 261120};
  int slot = img * K_SEL + i;
  unsigned k = selIdx[slot];
  unsigned sv = selSV[slot];
  int a = (int)(k % 3u); int r = (int)(k / 3u);
  int y = r >> (8 - lvl); int x = r & (f - 1);
  const float* dp = del.p[lvl] + (size_t)(img * 12 + a * 4) * hw + (size_t)y * f + x;
  float d0 = dp[0], d1 = dp[hw], d2 = dp[2 * hw], d3 = dp[3 * hw];
  const float* ar = anchors + (size_t)(aoffA[lvl] + (int)k) * 4;
  float a0 = ar[0], a1 = ar[1], a2 = ar[2], a3 = ar[3];
  // numpy-faithful, no FMA contraction
  float w = __fsub_rn(a2, a0), h = __fsub_rn(a3, a1);
  float cx = __fadd_rn(a0, __fmul_rn(0.5f, w));
  float cy = __fadd_rn(a1, __fmul_rn(0.5f, h));
  const float CLIP = 4.135166556742356f;     // log(1000/16)
  float dw = fminf(d2, CLIP), dh = fminf(d3, CLIP);
  float pcx = __fadd_rn(__fmul_rn(d0, w), cx);
  float pcy = __fadd_rn(__fmul_rn(d1, h), cy);
  float pw = __fmul_rn(expf(dw), w);
  float ph = __fmul_rn(expf(dh), h);
  float x1 = __fsub_rn(pcx, __fmul_rn(0.5f, pw));
  float y1 = __fsub_rn(pcy, __fmul_rn(0.5f, ph));
  float x2 = __fadd_rn(pcx, __fmul_rn(0.5f, pw));
  float y2 = __fadd_rn(pcy, __fmul_rn(0.5f, ph));
  float x1c = fminf(fmaxf(x1, 0.0f), 1024.0f);
  float y1c = fminf(fmaxf(y1, 0.0f), 1024.0f);
  float x2c = fminf(fmaxf(x2, 0.0f), 1024.0f);
  float y2c = fminf(fmaxf(y2, 0.0f), 1024.0f);
  bool valid = (__fsub_rn(x2c, x1c) >= 1e-3f) && (__fsub_rn(y2c, y1c) >= 1e-3f);
  float* bp = boxP + (size_t)slot * 4;
  bp[0] = x1c; bp[1] = y1c; bp[2] = x2c; bp[3] = y2c;
  unsigned low = 0xFFFFFFFFu - (unsigned)i;   // pos asc tie-break, unique keys
  keyP[slot] = valid ? (((unsigned long long)sv << 32) | low) : (unsigned long long)low;
}

// ---------------- global per-image stable sort by (logit desc, pos asc) via rank --------
__global__ __launch_bounds__(256) void k_sortrank(const unsigned long long* keyP, const float* boxP,
                                                  float* sBox, unsigned* sMeta) {
  __shared__ unsigned long long lk[K_SEL];
  int img = blockIdx.y;
  for (int t = threadIdx.x; t < K_SEL; t += 256) lk[t] = keyP[(size_t)img * K_SEL + t];
  __syncthreads();
  int i = blockIdx.x * 256 + threadIdx.x;
  if (i >= K_SEL) return;
  unsigned long long ki = lk[i];
  int rank = 0;
#pragma unroll 4
  for (int j = 0; j < K_SEL; ++j) rank += (lk[j] > ki) ? 1 : 0;
  int slot = img * K_SEL + i;
  const float* bp = boxP + (size_t)slot * 4;
  float* op = sBox + (size_t)(img * K_SEL + rank) * 4;
  op[0] = bp[0]; op[1] = bp[1]; op[2] = bp[2]; op[3] = bp[3];
  bool valid = (ki >> 32) != 0ULL;
  int pos = (int)(0xFFFFFFFFu - (unsigned)ki);
  int lvl = (pos < 4000) ? pos / 1000 : 4;
  sMeta[img * K_SEL + rank] = valid ? (unsigned)lvl : 255u;
}

// ---------------- IoU computed on OFFSET boxes, bitwise matching the reference ----------
__device__ __forceinline__ bool iou_gt(float rx1, float ry1, float rx2, float ry2, float rar,
                                       float cx1, float cy1, float cx2, float cy2, float car) {
  float ltx = fmaxf(rx1, cx1), lty = fmaxf(ry1, cy1);
  float rbx = fminf(rx2, cx2), rby = fminf(ry2, cy2);
  float wx = fmaxf(__fsub_rn(rbx, ltx), 0.0f);
  float wy = fmaxf(__fsub_rn(rby, lty), 0.0f);
  float inter = __fmul_rn(wx, wy);
  float denom = __fadd_rn(__fsub_rn(__fadd_rn(rar, car), inter), 1e-9f);
  return __fdiv_rn(inter, denom) > 0.7f;
}

// -------- upper-triangle 64x64 suppression bitmask, TRANSPOSED store maskT[c][i] --------
__global__ __launch_bounds__(64) void k_mask(const float* sBox, const unsigned* sMeta,
                                             unsigned long long* maskT) {
  int img = blockIdx.y;
  int q = blockIdx.x;                       // 0..2849 linear upper-triangle index
  int r = (int)((151.0f - sqrtf(22801.0f - 8.0f * (float)q)) * 0.5f);
  while ((r + 1) * (150 - r) / 2 <= q) ++r;          // C(r+1) <= q
  while (r * (151 - r) / 2 > q) --r;                 // C(r)  >  q
  int rowb = r;
  int colb = r + (q - r * (151 - r) / 2);
  int t = threadIdx.x;
  const float4* b4 = (const float4*)sBox;
  const unsigned* meta = sMeta + (size_t)img * K_SEL;
  __shared__ float cx1[64], cy1[64], cx2[64], cy2[64], car[64];
  int j = colb * 64 + t;
  if (j < K_SEL) {
    float4 bb = b4[(size_t)img * K_SEL + j];
    float off = __fmul_rn((float)meta[j], 1025.0f);
    float ox1 = __fadd_rn(bb.x, off), oy1 = __fadd_rn(bb.y, off);
    float ox2 = __fadd_rn(bb.z, off), oy2 = __fadd_rn(bb.w, off);
    cx1[t] = ox1; cy1[t] = oy1; cx2[t] = ox2; cy2[t] = oy2;
    car[t] = __fmul_rn(__fsub_rn(ox2, ox1), __fsub_rn(oy2, oy1));
  }
  __syncthreads();
  int i = rowb * 64 + t;
  if (i >= K_SEL) return;
  float4 rb = b4[(size_t)img * K_SEL + i];
  float off = __fmul_rn((float)meta[i], 1025.0f);
  float rx1 = __fadd_rn(rb.x, off), ry1 = __fadd_rn(rb.y, off);
  float rx2 = __fadd_rn(rb.z, off), ry2 = __fadd_rn(rb.w, off);
  float rar = __fmul_rn(__fsub_rn(rx2, rx1), __fsub_rn(ry2, ry1));
  unsigned long long bits = 0;
  int jmax = min(64, K_SEL - colb * 64);
  int jj0 = (rowb == colb) ? t + 1 : 0;     // off-diagonal blocks: every j > i already
  for (int jj = jj0; jj < jmax; ++jj) {
    if (iou_gt(rx1, ry1, rx2, ry2, rar, cx1[jj], cy1[jj], cx2[jj], cy2[jj], car[jj]))
      bits |= (1ULL << jj);
  }
  maskT[((size_t)img * W75 + colb) * K_SEL + i] = bits;   // coalesced
}

// --------- single-wave bit-scan, transposed gather of kept rows' word c -----------------
__global__ __launch_bounds__(64) void k_scan(const float* sBox, const unsigned* sMeta,
                                             const unsigned long long* maskT, float* out) {
  int img = blockIdx.x;
  int t = threadIdx.x;
  __shared__ int keptIdx[1000];
  const unsigned long long* mb = maskT + (size_t)img * W75 * K_SEL;
  const float4* boxes4 = (const float4*)(sBox + (size_t)img * K_SEL * 4);
  float4* out4 = (float4*)(out + (size_t)img * 1000 * 4);
  const unsigned* meta = sMeta + (size_t)img * K_SEL;
  int outc = 0;
  for (int c = 0; c < W75; ++c) {
    int i = c * 64 + t;
    bool inb = i < K_SEL;
    bool valid = inb && (meta[min(i, K_SEL - 1)] != 255u);
    unsigned long long validm = __ballot(valid);
    const unsigned long long* col = mb + (size_t)c * K_SEL;
    unsigned long long wself = inb ? col[i] : 0ULL;         // coalesced
    // gather OR of word c over all kept rows so far (independent loads, one wait)
    unsigned long long acc = 0;
    for (int kx = t; kx < outc; kx += 64) acc |= col[keptIdx[kx]];
#pragma unroll
    for (int d = 1; d < 64; d <<= 1) acc |= __shfl_xor(acc, d);
    unsigned long long candm = validm & ~acc;
    unsigned long long keepm = 0;
    int base = outc;
    while (candm) {
      int b = __ffsll(candm) - 1;
      keepm |= (1ULL << b);
      ++outc;
      if (outc == 1000) break;                              // later keeps can't reach output
      candm &= candm - 1;
      candm &= ~__shfl(wself, b);                           // within-chunk suppression
    }
    if ((keepm >> t) & 1ULL) {
      int rank = (int)__popcll(keepm & ((1ULL << t) - 1ULL));
      out4[base + rank] = boxes4[i];
      keptIdx[base + rank] = i;
    }
    __syncthreads();                                        // single wave: cheap; orders LDS
    if (outc >= 1000) break;
  }
}

// ---------------- path B fallback (small ws): barrier-sequential NMS --------------------
__global__ __launch_bounds__(256) void k_nmsseq(const float* sBox, const unsigned* sMeta,
                                                float* out) {
  int img = blockIdx.x;
  int t = threadIdx.x;
  __shared__ unsigned char keep[K_SEL];
  for (int i = t; i < K_SEL; i += 256) keep[i] = (sMeta[img * K_SEL + i] != 255u) ? 1 : 0;
  __syncthreads();
  for (int i = 0; i < K_SEL; ++i) {
    __syncthreads();
    if (!keep[i]) continue;
    unsigned lvi = sMeta[img * K_SEL + i];
    const float* bp = sBox + (size_t)(img * K_SEL + i) * 4;
    float off = __fmul_rn((float)lvi, 1025.0f);
    float rx1 = __fadd_rn(bp[0], off), ry1 = __fadd_rn(bp[1], off);
    float rx2 = __fadd_rn(bp[2], off), ry2 = __fadd_rn(bp[3], off);
    float rar = __fmul_rn(__fsub_rn(rx2, rx1), __fsub_rn(ry2, ry1));
    for (int j = i + 1 + t; j < K_SEL; j += 256) {
      if (!keep[j]) continue;
      unsigned lvj = sMeta[img * K_SEL + j];
      if (lvj != lvi) continue;
      const float* bq = sBox + (size_t)(img * K_SEL + j) * 4;
      float qx1 = __fadd_rn(bq[0], off), qy1 = __fadd_rn(bq[1], off);
      float qx2 = __fadd_rn(bq[2], off), qy2 = __fadd_rn(bq[3], off);
      float qar = __fmul_rn(__fsub_rn(qx2, qx1), __fsub_rn(qy2, qy1));
      if (iou_gt(rx1, ry1, rx2, ry2, rar, qx1, qy1, qx2, qy2, qar)) keep[j] = 0;
    }
  }
  __syncthreads();
  if (t == 0) {
    int outc = 0;
    for (int i = 0; i < K_SEL && outc < 1000; ++i) {
      if (!keep[i]) continue;
      const float* bp = sBox + (size_t)(img * K_SEL + i) * 4;
      float* op = out + ((size_t)img * 1000 + outc) * 4;
      op[0] = bp[0]; op[1] = bp[1]; op[2] = bp[2]; op[3] = bp[3];
      ++outc;
    }
  }
}

extern "C" void kernel_launch(void* const* d_in, const int* in_sizes, int n_in,
                              void* d_out, int out_size, void* d_ws, size_t ws_size,
                              hipStream_t stream) {
  (void)in_sizes; (void)n_in;
  // setup_inputs() dict order is INTERLEAVED: obj_l0, delta_l0, obj_l1, delta_l1, ..., anchors
  P5 obj, del;
  for (int i = 0; i < 5; ++i) {
    obj.p[i] = (const float*)d_in[2 * i];
    del.p[i] = (const float*)d_in[2 * i + 1];
  }
  const float* anchors = (const float*)d_in[10];
  float* out = (float*)d_out;
  char* ws = (char*)d_ws;

  // ws layout (bytes)
  unsigned* ghist             = (unsigned*)(ws + 0);             // 40*8192*4 = 1310720
  unsigned* cnt               = (unsigned*)(ws + 1310720);       // 160
  int* Bthr                   = (int*)(ws + 1310880);            // 160
  unsigned long long* candK   = (unsigned long long*)(ws + 1311040);   // 40*16384*8 = 5242880
  unsigned* selSV             = (unsigned*)(ws + 6553920);       // 152576
  unsigned* selIdx            = (unsigned*)(ws + 6706496);       // 152576
  float* boxP                 = (float*)(ws + 6859072);          // 610304
  unsigned long long* keyP    = (unsigned long long*)(ws + 7469376);   // 305152
  float* sBox                 = (float*)(ws + 7774528);          // 610304
  unsigned* sMeta             = (unsigned*)(ws + 8384832);       // 152576
  unsigned long long* maskT   = (unsigned long long*)(ws + 8537408);   // 8*75*4768*8 = 22878720
  const size_t NEED_A = 31416128ULL;   // everything incl. maskT
  const size_t NEED_B = 8537408ULL;    // everything except maskT
  bool pathA = ws_size >= NEED_A;
  bool pathB = !pathA && ws_size >= NEED_B;

  hipMemsetAsync(d_out, 0, (size_t)out_size * 4, stream);        // zero-padded output
  if (!pathA && !pathB) return;                                  // ws too small: diagnose, don't fault

  hipMemsetAsync(ws, 0, 1311040, stream);                        // hist + counters + Bthr

  k_hist   <<<dim3(8, 40), 256, 0, stream>>>(obj, ghist);
  k_thresh <<<40, 256, 0, stream>>>(ghist, Bthr);
  k_gather <<<dim3(64, 40), 256, 0, stream>>>(obj, Bthr, cnt, candK);
  k_select <<<dim3(64, 40), 256, 0, stream>>>(cnt, candK, selSV, selIdx);
  k_decode <<<dim3(19, 8), 256, 0, stream>>>(del, anchors, selSV, selIdx, boxP, keyP);
  k_sortrank<<<dim3(19, 8), 256, 0, stream>>>(keyP, boxP, sBox, sMeta);
  if (pathA) {
    k_mask <<<dim3(2850, 8), 64, 0, stream>>>(sBox, sMeta, maskT);
    k_scan <<<8, 64, 0, stream>>>(sBox, sMeta, maskT, out);
  } else {
    k_nmsseq<<<8, 256, 0, stream>>>(sBox, sMeta, out);
  }
}

// Round 5
// 593.453 us; speedup vs baseline: 2.1245x; 1.1080x over previous
//
#include <hip/hip_runtime.h>
#include <cstdint>

#define K_SEL 4768
#define W75 75
#define CAND_CAP 16384
#define NBIN 4096

struct P5 { const float* p[5]; };

__device__ __forceinline__ unsigned fsortkey(float f) {
  unsigned b = __float_as_uint(f);
  return (b & 0x80000000u) ? ~b : (b | 0x80000000u);
}

// ---------------- histogram of sortable-logit top-12 bits per (img,lvl) ----------------
__global__ __launch_bounds__(256) void k_hist(P5 obj, unsigned* ghist) {
  int p = blockIdx.y; int img = p / 5, lvl = p % 5;
  int f = 256 >> lvl; int n = 3 * f * f;
  __shared__ unsigned lh[NBIN];
  for (int b = threadIdx.x; b < NBIN; b += 256) lh[b] = 0;
  __syncthreads();
  int chunk = (n + gridDim.x - 1) / gridDim.x;
  int e0 = blockIdx.x * chunk, e1 = min(n, e0 + chunk);
  const float* src = obj.p[lvl] + (size_t)img * n;
  for (int e = e0 + threadIdx.x; e < e1; e += 256) {
    unsigned sv = fsortkey(src[e]);
    atomicAdd(&lh[sv >> 20], 1u);
  }
  __syncthreads();
  for (int b = threadIdx.x; b < NBIN; b += 256) {
    unsigned v = lh[b];
    if (v) atomicAdd(&ghist[(size_t)p * NBIN + b], v);
  }
}

// ---------------- find threshold bin B: count(bin >= B) >= kk --------------------------
__global__ __launch_bounds__(256) void k_thresh(const unsigned* ghist, int* Bthr) {
  int p = blockIdx.x; int lvl = p % 5;
  unsigned kk = (lvl == 4) ? 768u : 1000u;
  const unsigned* h = ghist + (size_t)p * NBIN;
  __shared__ unsigned csum[256];
  unsigned s = 0;
  int c = threadIdx.x;
  for (int b = 0; b < 16; ++b) s += h[c * 16 + b];
  csum[c] = s;
  __syncthreads();
  if (threadIdx.x == 0) {
    unsigned acc = 0; int B = 0;
    for (int cc = 255; cc >= 0; --cc) {
      if (acc + csum[cc] >= kk) {
        for (int b = 15; b >= 0; --b) {
          acc += h[cc * 16 + b];
          if (acc >= kk) { B = cc * 16 + b; break; }
        }
        break;
      }
      acc += csum[cc];
    }
    Bthr[p] = B;
  }
}

// ------- gather candidates (bin >= B), wave-aggregated atomics, grid-stride ------------
__global__ __launch_bounds__(256) void k_gather(P5 obj, const int* Bthr, unsigned* cnt,
                                                unsigned long long* ck) {
  int p = blockIdx.y; int img = p / 5, lvl = p % 5;
  int f = 256 >> lvl; int hw = f * f; int n = 3 * hw;
  int B = Bthr[p];
  int shift = 2 * (8 - lvl);
  const float* src = obj.p[lvl] + (size_t)img * n;
  unsigned long long* dst = ck + (size_t)p * CAND_CAP;
  int lane = threadIdx.x & 63;
  for (int e = blockIdx.x * 256 + threadIdx.x; e < n; e += gridDim.x * 256) {
    float v = src[e];
    unsigned sv = fsortkey(v);
    bool pass = (int)(sv >> 20) >= B;
    unsigned long long m = __ballot(pass);
    if (m) {
      int leader = __ffsll(m) - 1;
      unsigned base = 0;
      if (lane == leader) base = atomicAdd(&cnt[p], (unsigned)__popcll(m));
      base = __shfl(base, leader);
      if (pass) {
        unsigned pos = base + (unsigned)__popcll(m & ((1ULL << lane) - 1ULL));
        if (pos < CAND_CAP) {
          int a = e >> shift;            // e / hw
          int r = e & (hw - 1);          // e % hw
          unsigned kidx = (unsigned)(r * 3 + a);   // reference flatten order (y*W+x)*A + a
          dst[pos] = ((unsigned long long)sv << 32) | (unsigned)(0xFFFFFFFFu - kidx);
        }
      }
    }
  }
}

// ------- exact top-kk per level by rank counting, LDS-staged keys ----------------------
__global__ __launch_bounds__(256) void k_select(const unsigned* cnt, const unsigned long long* ck,
                                                unsigned* selSV, unsigned* selIdx) {
  int p = blockIdx.y; int img = p / 5, lvl = p % 5;
  int Cc = min((int)cnt[p], CAND_CAP);
  if (blockIdx.x * 256 >= Cc) return;
  int kk = (lvl == 4) ? 768 : 1000;
  int soff = lvl * 1000;
  const unsigned long long* keys = ck + (size_t)p * CAND_CAP;
  __shared__ unsigned long long sk[2048];
  int stage = min(Cc, 2048);
  for (int j = threadIdx.x; j < stage; j += 256) sk[j] = keys[j];
  __syncthreads();
  int c = blockIdx.x * 256 + threadIdx.x;
  if (c >= Cc) return;
  unsigned long long kc = keys[c];
  int rank = 0;
#pragma unroll 8
  for (int j = 0; j < stage; ++j) rank += (sk[j] > kc) ? 1 : 0;
  for (int j = stage; j < Cc; ++j) rank += (keys[j] > kc) ? 1 : 0;
  if (rank < kk) {
    int slot = img * K_SEL + soff + rank;
    selSV[slot]  = (unsigned)(kc >> 32);
    selIdx[slot] = 0xFFFFFFFFu - (unsigned)kc;
  }
}

// ---------------- decode + clip + validity for the 4768 selected per image --------------
__global__ __launch_bounds__(256) void k_decode(P5 del, const float* anchors,
                                                const unsigned* selSV, const unsigned* selIdx,
                                                float* boxP, unsigned long long* keyP) {
  int i = blockIdx.x * 256 + threadIdx.x;
  if (i >= K_SEL) return;
  int img = blockIdx.y;
  int lvl = (i < 4000) ? (i / 1000) : 4;
  int f = 256 >> lvl, hw = f * f;
  const int aoffA[5] = {0, 196608, 245760, 258048, 261120};
  int slot = img * K_SEL + i;
  unsigned k = selIdx[slot];
  unsigned sv = selSV[slot];
  int a = (int)(k % 3u); int r = (int)(k / 3u);
  int y = r >> (8 - lvl); int x = r & (f - 1);
  const float* dp = del.p[lvl] + (size_t)(img * 12 + a * 4) * hw + (size_t)y * f + x;
  float d0 = dp[0], d1 = dp[hw], d2 = dp[2 * hw], d3 = dp[3 * hw];
  const float* ar = anchors + (size_t)(aoffA[lvl] + (int)k) * 4;
  float a0 = ar[0], a1 = ar[1], a2 = ar[2], a3 = ar[3];
  // numpy-faithful, no FMA contraction
  float w = __fsub_rn(a2, a0), h = __fsub_rn(a3, a1);
  float cx = __fadd_rn(a0, __fmul_rn(0.5f, w));
  float cy = __fadd_rn(a1, __fmul_rn(0.5f, h));
  const float CLIP = 4.135166556742356f;     // log(1000/16)
  float dw = fminf(d2, CLIP), dh = fminf(d3, CLIP);
  float pcx = __fadd_rn(__fmul_rn(d0, w), cx);
  float pcy = __fadd_rn(__fmul_rn(d1, h), cy);
  float pw = __fmul_rn(expf(dw), w);
  float ph = __fmul_rn(expf(dh), h);
  float x1 = __fsub_rn(pcx, __fmul_rn(0.5f, pw));
  float y1 = __fsub_rn(pcy, __fmul_rn(0.5f, ph));
  float x2 = __fadd_rn(pcx, __fmul_rn(0.5f, pw));
  float y2 = __fadd_rn(pcy, __fmul_rn(0.5f, ph));
  float x1c = fminf(fmaxf(x1, 0.0f), 1024.0f);
  float y1c = fminf(fmaxf(y1, 0.0f), 1024.0f);
  float x2c = fminf(fmaxf(x2, 0.0f), 1024.0f);
  float y2c = fminf(fmaxf(y2, 0.0f), 1024.0f);
  bool valid = (__fsub_rn(x2c, x1c) >= 1e-3f) && (__fsub_rn(y2c, y1c) >= 1e-3f);
  float* bp = boxP + (size_t)slot * 4;
  bp[0] = x1c; bp[1] = y1c; bp[2] = x2c; bp[3] = y2c;
  unsigned low = 0xFFFFFFFFu - (unsigned)i;   // pos asc tie-break, unique keys
  keyP[slot] = valid ? (((unsigned long long)sv << 32) | low) : (unsigned long long)low;
}

// ------- global per-image stable sort; also precompute OFFSET boxes + areas -------------
__global__ __launch_bounds__(256) void k_sortrank(const unsigned long long* keyP, const float* boxP,
                                                  float* sBox, unsigned* sMeta,
                                                  float4* oBox4, float* oArea) {
  __shared__ unsigned long long lk[K_SEL];
  int img = blockIdx.y;
  for (int t = threadIdx.x; t < K_SEL; t += 256) lk[t] = keyP[(size_t)img * K_SEL + t];
  __syncthreads();
  int i = blockIdx.x * 256 + threadIdx.x;
  if (i >= K_SEL) return;
  unsigned long long ki = lk[i];
  int rank = 0;
#pragma unroll 8
  for (int j = 0; j < K_SEL; ++j) rank += (lk[j] > ki) ? 1 : 0;
  int slot = img * K_SEL + i;
  const float* bp = boxP + (size_t)slot * 4;
  float b0 = bp[0], b1 = bp[1], b2 = bp[2], b3 = bp[3];
  int oslot = img * K_SEL + rank;
  float* op = sBox + (size_t)oslot * 4;
  op[0] = b0; op[1] = b1; op[2] = b2; op[3] = b3;
  bool valid = (ki >> 32) != 0ULL;
  int pos = (int)(0xFFFFFFFFu - (unsigned)ki);
  int lvl = (pos < 4000) ? pos / 1000 : 4;
  unsigned mval = valid ? (unsigned)lvl : 255u;
  sMeta[oslot] = mval;
  float off = __fmul_rn((float)mval, 1025.0f);
  float ox1 = __fadd_rn(b0, off), oy1 = __fadd_rn(b1, off);
  float ox2 = __fadd_rn(b2, off), oy2 = __fadd_rn(b3, off);
  oBox4[oslot] = make_float4(ox1, oy1, ox2, oy2);
  oArea[oslot] = __fmul_rn(__fsub_rn(ox2, ox1), __fsub_rn(oy2, oy1));
}

// ---------------- IoU on precomputed offset boxes, bitwise matching reference -----------
__device__ __forceinline__ bool iou_gt(float rx1, float ry1, float rx2, float ry2, float rar,
                                       float cx1, float cy1, float cx2, float cy2, float car) {
  float ltx = fmaxf(rx1, cx1), lty = fmaxf(ry1, cy1);
  float rbx = fminf(rx2, cx2), rby = fminf(ry2, cy2);
  float wx = fmaxf(__fsub_rn(rbx, ltx), 0.0f);
  float wy = fmaxf(__fsub_rn(rby, lty), 0.0f);
  float inter = __fmul_rn(wx, wy);
  float denom = __fadd_rn(__fsub_rn(__fadd_rn(rar, car), inter), 1e-9f);
  return __fdiv_rn(inter, denom) > 0.7f;
}

// ---- upper-triangle suppression bitmask, 4 row-waves per block, transposed store -------
__global__ __launch_bounds__(256) void k_mask(const float4* oBox4, const float* oArea,
                                              unsigned long long* maskT) {
  int img = blockIdx.y;
  int q = blockIdx.x;                        // 0..740: (R,colb) with colb >= 4R
  // off(R) = 77R - 2R^2 ; invert
  int R = (int)((77.0f - sqrtf(5929.0f - 8.0f * (float)q)) * 0.25f);
  while (77 * (R + 1) - 2 * (R + 1) * (R + 1) <= q) ++R;
  while (77 * R - 2 * R * R > q) --R;
  int colb = 4 * R + (q - (77 * R - 2 * R * R));
  int tid = threadIdx.x;
  int w = tid >> 6, t = tid & 63;
  __shared__ float cx1[64], cy1[64], cx2[64], cy2[64], car[64];
  if (tid < 64) {
    int j = colb * 64 + tid;
    if (j < K_SEL) {
      float4 ob = oBox4[(size_t)img * K_SEL + j];
      cx1[tid] = ob.x; cy1[tid] = ob.y; cx2[tid] = ob.z; cy2[tid] = ob.w;
      car[tid] = oArea[(size_t)img * K_SEL + j];
    }
  }
  __syncthreads();
  int rowb = 4 * R + w;
  if (rowb > colb) return;
  int i = rowb * 64 + t;
  if (i >= K_SEL) return;
  float4 rb = oBox4[(size_t)img * K_SEL + i];
  float rar = oArea[(size_t)img * K_SEL + i];
  unsigned long long bits = 0;
  int jmax = min(64, K_SEL - colb * 64);
  int jj0 = (rowb == colb) ? t + 1 : 0;
  for (int jj = jj0; jj < jmax; ++jj) {
    if (iou_gt(rb.x, rb.y, rb.z, rb.w, rar, cx1[jj], cy1[jj], cx2[jj], cy2[jj], car[jj]))
      bits |= (1ULL << jj);
  }
  maskT[((size_t)img * W75 + colb) * K_SEL + i] = bits;   // coalesced across 256 rows
}

// --- single-wave bit-scan; gather of kept rows' word c with batched independent loads ---
__global__ __launch_bounds__(64) void k_scan(const float* sBox, const unsigned* sMeta,
                                             const unsigned long long* maskT, float* out) {
  int img = blockIdx.x;
  int t = threadIdx.x;
  __shared__ int keptIdx[1000];
  const unsigned long long* mb = maskT + (size_t)img * W75 * K_SEL;
  const float4* boxes4 = (const float4*)(sBox + (size_t)img * K_SEL * 4);
  float4* out4 = (float4*)(out + (size_t)img * 1000 * 4);
  const unsigned* meta = sMeta + (size_t)img * K_SEL;
  int outc = 0;
  for (int c = 0; c < W75; ++c) {
    int i = c * 64 + t;
    bool inb = i < K_SEL;
    bool valid = inb && (meta[inb ? i : 0] != 255u);
    unsigned long long validm = __ballot(valid);
    const unsigned long long* col = mb + (size_t)c * K_SEL;
    unsigned long long wself = inb ? col[i] : 0ULL;         // coalesced
    // OR of word c over kept rows so far: batches of independent loads
    unsigned long long acc = 0;
    int kx = t;
    while (kx + 448 < outc) {                               // 8-wide batch
      int i0 = keptIdx[kx],       i1 = keptIdx[kx + 64],  i2 = keptIdx[kx + 128], i3 = keptIdx[kx + 192];
      int i4 = keptIdx[kx + 256], i5 = keptIdx[kx + 320], i6 = keptIdx[kx + 384], i7 = keptIdx[kx + 448];
      unsigned long long v0 = col[i0], v1 = col[i1], v2 = col[i2], v3 = col[i3];
      unsigned long long v4 = col[i4], v5 = col[i5], v6 = col[i6], v7 = col[i7];
      acc |= (v0 | v1) | (v2 | v3) | ((v4 | v5) | (v6 | v7));
      kx += 512;
    }
    while (kx + 192 < outc) {                               // 4-wide batch
      int i0 = keptIdx[kx], i1 = keptIdx[kx + 64], i2 = keptIdx[kx + 128], i3 = keptIdx[kx + 192];
      unsigned long long v0 = col[i0], v1 = col[i1], v2 = col[i2], v3 = col[i3];
      acc |= (v0 | v1) | (v2 | v3);
      kx += 256;
    }
    while (kx < outc) { acc |= col[keptIdx[kx]]; kx += 64; }
#pragma unroll
    for (int d = 1; d < 64; d <<= 1) acc |= __shfl_xor(acc, d);
    unsigned long long candm = validm & ~acc;
    unsigned long long keepm = 0;
    int base = outc;
    while (candm) {
      int b = __ffsll(candm) - 1;
      keepm |= (1ULL << b);
      ++outc;
      if (outc == 1000) break;                              // later keeps can't reach output
      candm &= candm - 1;
      candm &= ~__shfl(wself, b);                           // within-chunk suppression
    }
    if ((keepm >> t) & 1ULL) {
      int rank = (int)__popcll(keepm & ((1ULL << t) - 1ULL));
      out4[base + rank] = boxes4[i];
      keptIdx[base + rank] = i;
    }
    __syncthreads();                                        // single wave: orders LDS
    if (outc >= 1000) break;
  }
}

// ---------------- path B fallback (small ws): barrier-sequential NMS --------------------
__global__ __launch_bounds__(256) void k_nmsseq(const float* sBox, const unsigned* sMeta,
                                                float* out) {
  int img = blockIdx.x;
  int t = threadIdx.x;
  __shared__ unsigned char keep[K_SEL];
  for (int i = t; i < K_SEL; i += 256) keep[i] = (sMeta[img * K_SEL + i] != 255u) ? 1 : 0;
  __syncthreads();
  for (int i = 0; i < K_SEL; ++i) {
    __syncthreads();
    if (!keep[i]) continue;
    unsigned lvi = sMeta[img * K_SEL + i];
    const float* bp = sBox + (size_t)(img * K_SEL + i) * 4;
    float off = __fmul_rn((float)lvi, 1025.0f);
    float rx1 = __fadd_rn(bp[0], off), ry1 = __fadd_rn(bp[1], off);
    float rx2 = __fadd_rn(bp[2], off), ry2 = __fadd_rn(bp[3], off);
    float rar = __fmul_rn(__fsub_rn(rx2, rx1), __fsub_rn(ry2, ry1));
    for (int j = i + 1 + t; j < K_SEL; j += 256) {
      if (!keep[j]) continue;
      unsigned lvj = sMeta[img * K_SEL + j];
      if (lvj != lvi) continue;
      const float* bq = sBox + (size_t)(img * K_SEL + j) * 4;
      float qx1 = __fadd_rn(bq[0], off), qy1 = __fadd_rn(bq[1], off);
      float qx2 = __fadd_rn(bq[2], off), qy2 = __fadd_rn(bq[3], off);
      float qar = __fmul_rn(__fsub_rn(qx2, qx1), __fsub_rn(qy2, qy1));
      if (iou_gt(rx1, ry1, rx2, ry2, rar, qx1, qy1, qx2, qy2, qar)) keep[j] = 0;
    }
  }
  __syncthreads();
  if (t == 0) {
    int outc = 0;
    for (int i = 0; i < K_SEL && outc < 1000; ++i) {
      if (!keep[i]) continue;
      const float* bp = sBox + (size_t)(img * K_SEL + i) * 4;
      float* op = out + ((size_t)img * 1000 + outc) * 4;
      op[0] = bp[0]; op[1] = bp[1]; op[2] = bp[2]; op[3] = bp[3];
      ++outc;
    }
  }
}

extern "C" void kernel_launch(void* const* d_in, const int* in_sizes, int n_in,
                              void* d_out, int out_size, void* d_ws, size_t ws_size,
                              hipStream_t stream) {
  (void)in_sizes; (void)n_in;
  // setup_inputs() dict order is INTERLEAVED: obj_l0, delta_l0, obj_l1, delta_l1, ..., anchors
  P5 obj, del;
  for (int i = 0; i < 5; ++i) {
    obj.p[i] = (const float*)d_in[2 * i];
    del.p[i] = (const float*)d_in[2 * i + 1];
  }
  const float* anchors = (const float*)d_in[10];
  float* out = (float*)d_out;
  char* ws = (char*)d_ws;

  // ws layout (bytes)
  unsigned* ghist             = (unsigned*)(ws + 0);                   // 40*4096*4 = 655360
  unsigned* cnt               = (unsigned*)(ws + 655360);              // 160
  int* Bthr                   = (int*)(ws + 655520);                   // 160
  unsigned long long* candK   = (unsigned long long*)(ws + 655680);    // 40*16384*8 = 5242880 -> 5898560
  // oBox4/oArea reuse the candK region (dead after k_select)
  float4* oBox4               = (float4*)(ws + 655680);                // 8*4768*16 = 610304
  float* oArea                = (float*)(ws + 1265984);                // 8*4768*4  = 152576
  unsigned* selSV             = (unsigned*)(ws + 5898560);             // 152576
  unsigned* selIdx            = (unsigned*)(ws + 6051136);             // 152576
  float* boxP                 = (float*)(ws + 6203712);                // 610304
  unsigned long long* keyP    = (unsigned long long*)(ws + 6814016);   // 305152
  float* sBox                 = (float*)(ws + 7119168);                // 610304
  unsigned* sMeta             = (unsigned*)(ws + 7729472);             // 152576
  unsigned long long* maskT   = (unsigned long long*)(ws + 7882048);   // 8*75*4768*8 = 22878720 -> 30760768
  const size_t NEED_A = 30760768ULL;   // everything incl. maskT
  const size_t NEED_B = 7882048ULL;    // everything except maskT
  bool pathA = ws_size >= NEED_A;
  bool pathB = !pathA && ws_size >= NEED_B;

  hipMemsetAsync(d_out, 0, (size_t)out_size * 4, stream);        // zero-padded output
  if (!pathA && !pathB) return;                                  // ws too small: diagnose, don't fault

  hipMemsetAsync(ws, 0, 655680, stream);                         // hist + counters + Bthr

  k_hist   <<<dim3(8, 40), 256, 0, stream>>>(obj, ghist);
  k_thresh <<<40, 256, 0, stream>>>(ghist, Bthr);
  k_gather <<<dim3(64, 40), 256, 0, stream>>>(obj, Bthr, cnt, candK);
  k_select <<<dim3(64, 40), 256, 0, stream>>>(cnt, candK, selSV, selIdx);
  k_decode <<<dim3(19, 8), 256, 0, stream>>>(del, anchors, selSV, selIdx, boxP, keyP);
  k_sortrank<<<dim3(19, 8), 256, 0, stream>>>(keyP, boxP, sBox, sMeta, oBox4, oArea);
  if (pathA) {
    k_mask <<<dim3(741, 8), 256, 0, stream>>>(oBox4, oArea, maskT);
    k_scan <<<8, 64, 0, stream>>>(sBox, sMeta, maskT, out);
  } else {
    k_nmsseq<<<8, 256, 0, stream>>>(sBox, sMeta, out);
  }
}